// Round 1
// baseline (88.418 us; speedup 1.0000x reference)
//
#include <hip/hip_runtime.h>
#include <math.h>

// Problem constants (KAN_layer_1108101562900): B=8192, IN_F=OUT_F=1024, GRID=5.
// idx_in = arange(1024) % 1024 == identity  =>  x = X directly.
//
// spline(t), t = 2*clamp(x,-1,1)+2 in [0,4], G=5 knots, is piecewise linear
// with integer breakpoints => exact ramp-sum form:
//   s(t) = c0 + sum_i (c[i+1]-c[i]) * clamp(t - i, 0, 1)
// No dynamic indexing -> pure VALU (min/max + fma), no LDS/scratch.

#define B_ROWS   8192
#define N_FEAT   1024
#define N_BLOCKS 2048
#define ROWS_PER_BLOCK (B_ROWS / N_BLOCKS)   // 4

__global__ __launch_bounds__(256) void kan_kernel(
    const float* __restrict__ X,
    const float* __restrict__ coeffs,   // (1024, 5) row-major
    const float* __restrict__ W,        // (1024, 2) row-major
    const float* __restrict__ bias,     // (1024,)
    float* __restrict__ Y)
{
    const int t    = threadIdx.x;   // 0..255
    const int col0 = t * 4;         // this thread owns columns col0..col0+3

    // ---- per-column params, loop-invariant, held in registers (32 VGPRs) ----
    float c0[4], d0[4], d1[4], d2[4], d3[4], w0[4], w1[4], bb[4];
#pragma unroll
    for (int j = 0; j < 4; ++j) {
        const int col = col0 + j;
        const float* cp = coeffs + col * 5;
        const float a0 = cp[0], a1 = cp[1], a2 = cp[2], a3 = cp[3], a4 = cp[4];
        c0[j] = a0;
        d0[j] = a1 - a0;
        d1[j] = a2 - a1;
        d2[j] = a3 - a2;
        d3[j] = a4 - a3;
        w0[j] = W[col * 2 + 0];
        w1[j] = W[col * 2 + 1];
        bb[j] = bias[col];
    }

    // ---- 4 rows per block, fully unrolled for load-level parallelism ----
#pragma unroll
    for (int i = 0; i < ROWS_PER_BLOCK; ++i) {
        const int row = blockIdx.x + i * N_BLOCKS;
        const size_t base = (size_t)row * N_FEAT + col0;

        const float4 x4 = *reinterpret_cast<const float4*>(X + base);
        const float xs[4] = {x4.x, x4.y, x4.z, x4.w};
        float ys[4];

#pragma unroll
        for (int j = 0; j < 4; ++j) {
            const float x = xs[j];

            // silu(x) = x * sigmoid(x)  (raw x, per reference)
            const float sig  = 1.0f / (1.0f + __expf(-x));
            const float silu = x * sig;

            // b-spline linear via ramp sum (exact for G=5)
            const float xc = fminf(fmaxf(x, -1.0f), 1.0f);
            const float tt = fmaf(2.0f, xc, 2.0f);            // [0,4]
            const float r0 = fminf(tt, 1.0f);                  // tt >= 0 already
            const float r1 = fminf(fmaxf(tt - 1.0f, 0.0f), 1.0f);
            const float r2 = fminf(fmaxf(tt - 2.0f, 0.0f), 1.0f);
            const float r3 = fminf(fmaxf(tt - 3.0f, 0.0f), 1.0f);
            float s = c0[j];
            s = fmaf(d0[j], r0, s);
            s = fmaf(d1[j], r1, s);
            s = fmaf(d2[j], r2, s);
            s = fmaf(d3[j], r3, s);

            ys[j] = fmaf(silu, w0[j], fmaf(s, w1[j], bb[j]));
        }

        *reinterpret_cast<float4*>(Y + base) =
            make_float4(ys[0], ys[1], ys[2], ys[3]);
    }
}

extern "C" void kernel_launch(void* const* d_in, const int* in_sizes, int n_in,
                              void* d_out, int out_size, void* d_ws, size_t ws_size,
                              hipStream_t stream) {
    const float* X      = (const float*)d_in[0];   // (8192, 1024)
    const float* coeffs = (const float*)d_in[1];   // (1024, 5)
    const float* W      = (const float*)d_in[2];   // (1024, 2)
    const float* b      = (const float*)d_in[3];   // (1024,)
    float* Y            = (float*)d_out;           // (8192, 1024)

    kan_kernel<<<N_BLOCKS, 256, 0, stream>>>(X, coeffs, W, b, Y);
}